// Round 6
// baseline (1959.524 us; speedup 1.0000x reference)
//
#include <hip/hip_runtime.h>

#define B_  16
#define T_  12
#define N_  1024
#define K_  3
#define H_  64
#define DIN 65
#define KH  192   // K_*H_
#define OG  128   // 2*H_

typedef _Float16 f16x4 __attribute__((ext_vector_type(4)));
typedef float    f32x4 __attribute__((ext_vector_type(4)));

// ---- workspace offsets (float units), total 6,670,912 f = 26.7 MB ----
static const size_t OFF_H   = 0;          // f32 h   [16][1024][64]
static const size_t OFF_ZB  = 1048576;    // f32 z   [16][1024][64]
static const size_t OFF_S2  = 2097152;    // f32 S2  [16][3][12][1024] (x1024)
static const size_t OFF_ZF  = 2686976;    // f16 Z   [16][1024][192]   (x1024)
static const size_t OFF_HT  = 4259840;    // f16 Ht  [16][64][1024]
static const size_t OFF_YT  = 4784128;    // f16 Yt  [16][192][1024]
static const size_t OFF_S1  = 6356992;    // f16 S1  [3][192][1024]
static const size_t OFF_WGT = 6651904;    // f16 wghT [128][192] (/1024)
static const size_t OFF_WUT = 6664192;    // f16 wuhT [64][192]  (/1024)
static const size_t OFF_WX  = 6670336;    // f32 wx: [0..383]=gate [3][128], [384..575]=upd [3][64] (/1024)

// Repack weights: transposed f16 h-part + f32 x-part rows, all pre-divided by 1024.
__global__ __launch_bounds__(256) void k_repack(const float* __restrict__ Wg,
                                                const float* __restrict__ Wu,
                                                _Float16* __restrict__ wghT,
                                                _Float16* __restrict__ wuhT,
                                                float* __restrict__ wx) {
    const float inv = 1.0f / 1024.0f;
    int idx = blockIdx.x * 256 + threadIdx.x;
    if (idx < 128 * 192) {                       // wghT[o][d], d = k*64+c
        int o = idx / 192, d = idx % 192;
        int k = d / 64, c = d % 64;
        wghT[idx] = (_Float16)(Wg[(size_t)(k * DIN + 1 + c) * OG + o] * inv);
    } else if (idx < 128 * 192 + 64 * 192) {     // wuhT[o][d]
        int j = idx - 128 * 192;
        int o = j / 192, d = j % 192;
        int k = d / 64, c = d % 64;
        wuhT[j] = (_Float16)(Wu[(size_t)(k * DIN + 1 + c) * H_ + o] * inv);
    } else if (idx < 128 * 192 + 64 * 192 + 576) {
        int j = idx - 128 * 192 - 64 * 192;
        if (j < 384) { int k = j >> 7, o = j & 127; wx[j] = Wg[(size_t)(k * DIN) * OG + o] * inv; }
        else { int j2 = j - 384; int k = j2 >> 6, o = j2 & 63; wx[j] = Wu[(size_t)(k * DIN) * H_ + o] * inv; }
    }
}

// S1[k][m][i] = sum_j G[k][i][j] x[m][j]  (f16 out). grid 96: kk*32 + it*2 + nh
__global__ __launch_bounds__(256) void k_s1b(const float* __restrict__ G,
                                             const float* __restrict__ x,
                                             _Float16* __restrict__ S1) {
    int bx = blockIdx.x;
    int nh = bx & 1, it = (bx >> 1) & 15, kk = bx >> 5;
    int i0 = it * 64, m0 = nh * 96;
    __shared__ _Float16 sA[64][72], sB[96][72];
    int tid = threadIdx.x, wid = tid >> 6, ln = tid & 15, kl = (tid & 63) >> 4;
    const float* Gk = G + (size_t)kk * N_ * N_;
    f32x4 acc[6];
    #pragma unroll
    for (int n = 0; n < 6; ++n) acc[n] = (f32x4){0.f, 0.f, 0.f, 0.f};
    for (int kc = 0; kc < N_; kc += 64) {
        #pragma unroll
        for (int it2 = 0; it2 < 4; ++it2) {
            int idx = it2 * 256 + tid; int row = idx >> 4, c4 = (idx & 15) * 4;
            float4 g = *(const float4*)&Gk[(size_t)(i0 + row) * N_ + kc + c4];
            f16x4 hv = {(_Float16)g.x, (_Float16)g.y, (_Float16)g.z, (_Float16)g.w};
            *(f16x4*)&sA[row][c4] = hv;
        }
        #pragma unroll
        for (int it2 = 0; it2 < 6; ++it2) {
            int idx = it2 * 256 + tid; int row = idx >> 4, c4 = (idx & 15) * 4;
            float4 g = *(const float4*)&x[(size_t)(m0 + row) * N_ + kc + c4];
            f16x4 hv = {(_Float16)g.x, (_Float16)g.y, (_Float16)g.z, (_Float16)g.w};
            *(f16x4*)&sB[row][c4] = hv;
        }
        __syncthreads();
        #pragma unroll
        for (int ks = 0; ks < 4; ++ks) {
            int ko = ks * 16 + kl * 4;
            f16x4 a = *(const f16x4*)&sA[wid * 16 + ln][ko];
            #pragma unroll
            for (int n = 0; n < 6; ++n) {
                f16x4 b = *(const f16x4*)&sB[n * 16 + ln][ko];
                acc[n] = __builtin_amdgcn_mfma_f32_16x16x16f16(a, b, acc[n], 0, 0, 0);
            }
        }
        __syncthreads();
    }
    #pragma unroll
    for (int n = 0; n < 6; ++n) {
        int m = m0 + n * 16 + ln;
        #pragma unroll
        for (int r = 0; r < 4; ++r) {
            int i = i0 + wid * 16 + kl * 4 + r;
            S1[(((size_t)kk * 192 + m) << 10) + i] = (_Float16)acc[n][r];
        }
    }
}

// S2[b][k][t][i] = sum_j (1024 A[b][i][j]) S1[k][b*12+t][j]  (f32 out). grid 256
__global__ __launch_bounds__(256) void k_s2b(const float* __restrict__ A,
                                             const _Float16* __restrict__ S1,
                                             float* __restrict__ S2) {
    int bx = blockIdx.x; int it = bx & 15, b = bx >> 4; int i0 = it * 64;
    __shared__ _Float16 sA[64][72], sB[48][72];
    int tid = threadIdx.x, wid = tid >> 6, ln = tid & 15, kl = (tid & 63) >> 4;
    const float* Ab = A + (size_t)b * N_ * N_;
    f32x4 acc[3];
    #pragma unroll
    for (int n = 0; n < 3; ++n) acc[n] = (f32x4){0.f, 0.f, 0.f, 0.f};
    for (int kc = 0; kc < N_; kc += 64) {
        #pragma unroll
        for (int it2 = 0; it2 < 4; ++it2) {
            int idx = it2 * 256 + tid; int row = idx >> 4, c4 = (idx & 15) * 4;
            float4 a4 = *(const float4*)&Ab[(size_t)(i0 + row) * N_ + kc + c4];
            f16x4 hv = {(_Float16)(a4.x * 1024.f), (_Float16)(a4.y * 1024.f),
                        (_Float16)(a4.z * 1024.f), (_Float16)(a4.w * 1024.f)};
            *(f16x4*)&sA[row][c4] = hv;
        }
        for (int idx = tid; idx < 288; idx += 256) {
            int row = idx >> 3, c8 = (idx & 7) * 8;
            int kq = row / 12, tq = row - kq * 12;
            *(uint4*)&sB[row][c8] = *(const uint4*)&S1[(((size_t)kq * 192 + b * T_ + tq) << 10) + kc + c8];
        }
        __syncthreads();
        #pragma unroll
        for (int ks = 0; ks < 4; ++ks) {
            int ko = ks * 16 + kl * 4;
            f16x4 a = *(const f16x4*)&sA[wid * 16 + ln][ko];
            #pragma unroll
            for (int n = 0; n < 3; ++n) {
                f16x4 b = *(const f16x4*)&sB[n * 16 + ln][ko];
                acc[n] = __builtin_amdgcn_mfma_f32_16x16x16f16(a, b, acc[n], 0, 0, 0);
            }
        }
        __syncthreads();
    }
    #pragma unroll
    for (int n = 0; n < 3; ++n) {
        int col = n * 16 + ln;
        if (col < 36) {
            int kq = col / 12, tq = col - kq * 12;
            #pragma unroll
            for (int r = 0; r < 4; ++r) {
                int i = i0 + wid * 16 + kl * 4 + r;
                S2[(((size_t)(b * 3 + kq) * T_ + tq) << 10) + i] = acc[n][r];
            }
        }
    }
}

// Stage 1: Yt[b][kk*64+c][i] = sum_j Ht[b][c][j] G[kk][i][j]. grid 768: (kk*16+it)*16+b
__global__ __launch_bounds__(256) void k_gh2(const float* __restrict__ G,
                                             const _Float16* __restrict__ Ht,
                                             _Float16* __restrict__ Yt) {
    int bx = blockIdx.x;
    int b = bx & 15, rest = bx >> 4;
    int it = rest & 15, kk = rest >> 4;
    int i0 = it * 64;
    __shared__ _Float16 sA[64][72], sB[64][72];
    int tid = threadIdx.x, wid = tid >> 6, ln = tid & 15, kl = (tid & 63) >> 4;
    const float* Gk = G + (size_t)kk * N_ * N_;
    const _Float16* Hb = Ht + ((size_t)b << 16);
    f32x4 acc[4];
    #pragma unroll
    for (int m = 0; m < 4; ++m) acc[m] = (f32x4){0.f, 0.f, 0.f, 0.f};
    for (int kc = 0; kc < N_; kc += 64) {
        #pragma unroll
        for (int it2 = 0; it2 < 2; ++it2) {          // Ht: 64x64 halves direct copy
            int idx = it2 * 256 + tid; int row = idx >> 3, c8 = (idx & 7) * 8;
            *(uint4*)&sA[row][c8] = *(const uint4*)&Hb[((size_t)row << 10) + kc + c8];
        }
        #pragma unroll
        for (int it2 = 0; it2 < 4; ++it2) {          // G: 64x64 f32 -> f16
            int idx = it2 * 256 + tid; int row = idx >> 4, c4 = (idx & 15) * 4;
            float4 g = *(const float4*)&Gk[(size_t)(i0 + row) * N_ + kc + c4];
            f16x4 hv = {(_Float16)g.x, (_Float16)g.y, (_Float16)g.z, (_Float16)g.w};
            *(f16x4*)&sB[row][c4] = hv;
        }
        __syncthreads();
        #pragma unroll
        for (int ks = 0; ks < 4; ++ks) {
            int ko = ks * 16 + kl * 4;
            f16x4 bfr = *(const f16x4*)&sB[wid * 16 + ln][ko];
            #pragma unroll
            for (int m = 0; m < 4; ++m) {
                f16x4 a = *(const f16x4*)&sA[m * 16 + ln][ko];
                acc[m] = __builtin_amdgcn_mfma_f32_16x16x16f16(a, bfr, acc[m], 0, 0, 0);
            }
        }
        __syncthreads();
    }
    int i = i0 + wid * 16 + ln;
    #pragma unroll
    for (int m = 0; m < 4; ++m)
        #pragma unroll
        for (int r = 0; r < 4; ++r) {
            int c = m * 16 + kl * 4 + r;
            Yt[(((size_t)b * 192 + kk * 64 + c) << 10) + i] = (_Float16)acc[m][r];
        }
}

// Stage 2: Zf[b][i][c] = sum_j (1024 A[b][i][j]) Yt[b][c][j]  (f16 out). grid 512
__global__ __launch_bounds__(256) void k_az2(const float* __restrict__ A,
                                             const _Float16* __restrict__ Yt,
                                             _Float16* __restrict__ Zf) {
    int bx = blockIdx.x;
    int nh = bx & 1, it = (bx >> 1) & 15, b = bx >> 5;
    int i0 = it * 64, c0 = nh * 96;
    __shared__ _Float16 sA[64][72], sB[96][72];
    int tid = threadIdx.x, wid = tid >> 6, ln = tid & 15, kl = (tid & 63) >> 4;
    const float* Ab = A + (size_t)b * N_ * N_;
    const _Float16* Yb = Yt + (((size_t)b * 192 + c0) << 10);
    f32x4 acc[6];
    #pragma unroll
    for (int n = 0; n < 6; ++n) acc[n] = (f32x4){0.f, 0.f, 0.f, 0.f};
    for (int kc = 0; kc < N_; kc += 64) {
        #pragma unroll
        for (int it2 = 0; it2 < 4; ++it2) {
            int idx = it2 * 256 + tid; int row = idx >> 4, c4 = (idx & 15) * 4;
            float4 a4 = *(const float4*)&Ab[(size_t)(i0 + row) * N_ + kc + c4];
            f16x4 hv = {(_Float16)(a4.x * 1024.f), (_Float16)(a4.y * 1024.f),
                        (_Float16)(a4.z * 1024.f), (_Float16)(a4.w * 1024.f)};
            *(f16x4*)&sA[row][c4] = hv;
        }
        #pragma unroll
        for (int it2 = 0; it2 < 3; ++it2) {
            int idx = it2 * 256 + tid; int row = idx >> 3, c8 = (idx & 7) * 8;
            *(uint4*)&sB[row][c8] = *(const uint4*)&Yb[((size_t)row << 10) + kc + c8];
        }
        __syncthreads();
        #pragma unroll
        for (int ks = 0; ks < 4; ++ks) {
            int ko = ks * 16 + kl * 4;
            f16x4 a = *(const f16x4*)&sA[wid * 16 + ln][ko];
            #pragma unroll
            for (int n = 0; n < 6; ++n) {
                f16x4 b = *(const f16x4*)&sB[n * 16 + ln][ko];
                acc[n] = __builtin_amdgcn_mfma_f32_16x16x16f16(a, b, acc[n], 0, 0, 0);
            }
        }
        __syncthreads();
    }
    #pragma unroll
    for (int n = 0; n < 6; ++n) {
        int c = c0 + n * 16 + ln;
        #pragma unroll
        for (int r = 0; r < 4; ++r) {
            int i = i0 + wid * 16 + kl * 4 + r;
            Zf[((size_t)((b << 10) + i)) * 192 + c] = (_Float16)acc[n][r];
        }
    }
}

// gate epilogue via MFMA: pre = Z@wghT^T + xt + bias; z->zb; r*h -> Ht. grid 256
__global__ __launch_bounds__(256) void k_zrm(const _Float16* __restrict__ Zf,
                                             const _Float16* __restrict__ wghT,
                                             const float* __restrict__ wx,
                                             const float* __restrict__ bg,
                                             const float* __restrict__ S2,
                                             const float* __restrict__ h,
                                             float* __restrict__ zb,
                                             _Float16* __restrict__ Ht, int t) {
    int bx = blockIdx.x; int it = bx & 15, b = bx >> 4; int i0 = it * 64;
    __shared__ _Float16 sZ[64][200];
    __shared__ _Float16 sW[128][72];
    __shared__ float sS2[3][64];
    __shared__ float sWX[3][128];
    __shared__ float sBias[128];
    int tid = threadIdx.x, wid = tid >> 6, ln = tid & 15, kl = (tid & 63) >> 4;
    #pragma unroll
    for (int it2 = 0; it2 < 6; ++it2) {
        int idx = it2 * 256 + tid; int row = idx / 24, c8 = (idx % 24) * 8;
        *(uint4*)&sZ[row][c8] = *(const uint4*)&Zf[((size_t)((b << 10) + i0 + row)) * 192 + c8];
    }
    if (tid < 192) { int k = tid >> 6, ii = tid & 63; sS2[k][ii] = S2[(((size_t)(b * 3 + k) * T_ + t) << 10) + i0 + ii]; }
    for (int q = tid; q < 384; q += 256) sWX[q >> 7][q & 127] = wx[q];
    if (tid < 128) sBias[tid] = bg[tid];
    f32x4 acc[4][2];
    #pragma unroll
    for (int m = 0; m < 4; ++m)
        #pragma unroll
        for (int n = 0; n < 2; ++n) acc[m][n] = (f32x4){0.f, 0.f, 0.f, 0.f};
    for (int kc = 0; kc < 192; kc += 64) {
        #pragma unroll
        for (int it2 = 0; it2 < 4; ++it2) {
            int idx = it2 * 256 + tid; int row = idx >> 3, c8 = (idx & 7) * 8;
            *(uint4*)&sW[row][c8] = *(const uint4*)&wghT[(size_t)row * 192 + kc + c8];
        }
        __syncthreads();
        #pragma unroll
        for (int ks = 0; ks < 4; ++ks) {
            int ko = ks * 16 + kl * 4;
            f16x4 a[4], bb[2];
            #pragma unroll
            for (int m = 0; m < 4; ++m) a[m] = *(const f16x4*)&sZ[m * 16 + ln][kc + ko];
            #pragma unroll
            for (int n = 0; n < 2; ++n) bb[n] = *(const f16x4*)&sW[wid * 32 + n * 16 + ln][ko];
            #pragma unroll
            for (int m = 0; m < 4; ++m)
                #pragma unroll
                for (int n = 0; n < 2; ++n)
                    acc[m][n] = __builtin_amdgcn_mfma_f32_16x16x16f16(a[m], bb[n], acc[m][n], 0, 0, 0);
        }
        __syncthreads();
    }
    #pragma unroll
    for (int n = 0; n < 2; ++n) {
        int o = wid * 32 + n * 16 + ln;
        float wx0 = sWX[0][o], wx1 = sWX[1][o], wx2 = sWX[2][o], bias = sBias[o];
        if (o < H_) {
            #pragma unroll
            for (int m = 0; m < 4; ++m)
                #pragma unroll
                for (int r = 0; r < 4; ++r) {
                    int il = m * 16 + kl * 4 + r;
                    float pre = acc[m][n][r] + wx0 * sS2[0][il] + wx1 * sS2[1][il] + wx2 * sS2[2][il] + bias;
                    float v = 1.0f / (1.0f + expf(-pre));
                    zb[((size_t)((b << 10) + i0 + il)) * H_ + o] = v;
                }
        } else {
            int c = o - H_;
            #pragma unroll
            for (int m = 0; m < 4; ++m) {
                alignas(8) _Float16 hb[4];
                #pragma unroll
                for (int r = 0; r < 4; ++r) {
                    int il = m * 16 + kl * 4 + r;
                    float pre = acc[m][n][r] + wx0 * sS2[0][il] + wx1 * sS2[1][il] + wx2 * sS2[2][il] + bias;
                    float v = 1.0f / (1.0f + expf(-pre));
                    hb[r] = (_Float16)(v * h[((size_t)((b << 10) + i0 + il)) * H_ + c]);
                }
                *(f16x4*)&Ht[(((size_t)(b * 64 + c)) << 10) + i0 + m * 16 + kl * 4] = *(f16x4*)&hb[0];
            }
        }
    }
}

// update epilogue via MFMA: hc = tanh(...); h = z*hc + (1-z)h; write h f32 + Ht f16. grid 256
__global__ __launch_bounds__(256) void k_updm(const _Float16* __restrict__ Zf,
                                              const _Float16* __restrict__ wuhT,
                                              const float* __restrict__ wx,
                                              const float* __restrict__ bu,
                                              const float* __restrict__ S2,
                                              const float* __restrict__ zb,
                                              float* __restrict__ h,
                                              _Float16* __restrict__ Ht, int t) {
    int bx = blockIdx.x; int it = bx & 15, b = bx >> 4; int i0 = it * 64;
    __shared__ _Float16 sZ[64][200];
    __shared__ _Float16 sW[64][72];
    __shared__ float sS2[3][64];
    __shared__ float sWX[3][64];
    __shared__ float sBias[64];
    int tid = threadIdx.x, wid = tid >> 6, ln = tid & 15, kl = (tid & 63) >> 4;
    #pragma unroll
    for (int it2 = 0; it2 < 6; ++it2) {
        int idx = it2 * 256 + tid; int row = idx / 24, c8 = (idx % 24) * 8;
        *(uint4*)&sZ[row][c8] = *(const uint4*)&Zf[((size_t)((b << 10) + i0 + row)) * 192 + c8];
    }
    if (tid < 192) { int k = tid >> 6, ii = tid & 63; sS2[k][ii] = S2[(((size_t)(b * 3 + k) * T_ + t) << 10) + i0 + ii]; }
    if (tid < 192) sWX[tid / 64][tid % 64] = wx[384 + tid];
    if (tid < 64) sBias[tid] = bu[tid];
    f32x4 acc[4];
    #pragma unroll
    for (int m = 0; m < 4; ++m) acc[m] = (f32x4){0.f, 0.f, 0.f, 0.f};
    for (int kc = 0; kc < 192; kc += 64) {
        #pragma unroll
        for (int it2 = 0; it2 < 2; ++it2) {
            int idx = it2 * 256 + tid; int row = idx >> 3, c8 = (idx & 7) * 8;
            *(uint4*)&sW[row][c8] = *(const uint4*)&wuhT[(size_t)row * 192 + kc + c8];
        }
        __syncthreads();
        #pragma unroll
        for (int ks = 0; ks < 4; ++ks) {
            int ko = ks * 16 + kl * 4;
            f16x4 bb = *(const f16x4*)&sW[wid * 16 + ln][ko];
            #pragma unroll
            for (int m = 0; m < 4; ++m) {
                f16x4 a = *(const f16x4*)&sZ[m * 16 + ln][kc + ko];
                acc[m] = __builtin_amdgcn_mfma_f32_16x16x16f16(a, bb, acc[m], 0, 0, 0);
            }
        }
        __syncthreads();
    }
    int o = wid * 16 + ln;
    float wx0 = sWX[0][o], wx1 = sWX[1][o], wx2 = sWX[2][o], bias = sBias[o];
    #pragma unroll
    for (int m = 0; m < 4; ++m) {
        alignas(8) _Float16 hb[4];
        #pragma unroll
        for (int r = 0; r < 4; ++r) {
            int il = m * 16 + kl * 4 + r;
            float pre = acc[m][r] + wx0 * sS2[0][il] + wx1 * sS2[1][il] + wx2 * sS2[2][il] + bias;
            float hc = tanhf(pre);
            size_t gi = ((size_t)((b << 10) + i0 + il)) * H_ + o;
            float z = zb[gi], hold = h[gi];
            float hn = z * hc + (1.0f - z) * hold;
            h[gi] = hn;
            hb[r] = (_Float16)hn;
        }
        *(f16x4*)&Ht[(((size_t)(b * 64 + o)) << 10) + i0 + m * 16 + kl * 4] = *(f16x4*)&hb[0];
    }
}

// out[(b*12+tt)*1024 + i] = h[b][i][:] @ W_dec[:,tt] + b_dec[tt]
__global__ __launch_bounds__(256) void k_dec(const float* __restrict__ h,
                                             const float* __restrict__ Wd,
                                             const float* __restrict__ bd,
                                             float* __restrict__ out) {
    int bx = blockIdx.x;
    int b = bx >> 4, it = bx & 15; int i0 = it * 64;
    __shared__ float hs[64][65];
    __shared__ float Wds[64][12];
    __shared__ float bds[12];
    int tid = threadIdx.x;
    for (int idx = tid; idx < 4096; idx += 256) {
        int r = idx >> 6, c = idx & 63;
        hs[r][c] = h[(size_t)(b * N_ + i0 + r) * H_ + c];
    }
    for (int idx = tid; idx < 768; idx += 256)
        Wds[idx / 12][idx % 12] = Wd[idx];
    if (tid < 12) bds[tid] = bd[tid];
    __syncthreads();
    for (int oidx = tid; oidx < 768; oidx += 256) {
        int i = oidx & 63, tt = oidx >> 6;
        float acc = bds[tt];
        #pragma unroll
        for (int c = 0; c < 64; ++c) acc += hs[i][c] * Wds[c][tt];
        out[(size_t)(b * T_ + tt) * N_ + i0 + i] = acc;
    }
}

extern "C" void kernel_launch(void* const* d_in, const int* in_sizes, int n_in,
                              void* d_out, int out_size, void* d_ws, size_t ws_size,
                              hipStream_t stream) {
    const float* x  = (const float*)d_in[0];
    const float* G  = (const float*)d_in[1];
    const float* A  = (const float*)d_in[2];
    const float* Wg = (const float*)d_in[3];
    const float* bg = (const float*)d_in[4];
    const float* Wu = (const float*)d_in[5];
    const float* bu = (const float*)d_in[6];
    const float* Wd = (const float*)d_in[7];
    const float* bd = (const float*)d_in[8];
    float* out = (float*)d_out;
    float* ws  = (float*)d_ws;

    float* h   = ws + OFF_H;
    float* zb  = ws + OFF_ZB;
    float* S2  = ws + OFF_S2;
    float* wxb = ws + OFF_WX;
    _Float16* Zf   = (_Float16*)(ws + OFF_ZF);
    _Float16* Ht   = (_Float16*)(ws + OFF_HT);
    _Float16* Yt   = (_Float16*)(ws + OFF_YT);
    _Float16* S1   = (_Float16*)(ws + OFF_S1);
    _Float16* wghT = (_Float16*)(ws + OFF_WGT);
    _Float16* wuhT = (_Float16*)(ws + OFF_WUT);

    hipMemsetAsync(h, 0, (size_t)B_ * N_ * H_ * sizeof(float), stream);
    hipMemsetAsync((void*)Ht, 0, (size_t)B_ * N_ * H_ * sizeof(_Float16), stream);
    k_repack<<<147, 256, 0, stream>>>(Wg, Wu, wghT, wuhT, wxb);
    k_s1b<<<96, 256, 0, stream>>>(G, x, S1);
    k_s2b<<<256, 256, 0, stream>>>(A, S1, S2);

    for (int t = 0; t < T_; ++t) {
        k_gh2<<<768, 256, 0, stream>>>(G, Ht, Yt);
        k_az2<<<512, 256, 0, stream>>>(A, Yt, Zf);
        k_zrm<<<256, 256, 0, stream>>>(Zf, wghT, wxb, bg, S2, h, zb, Ht, t);
        k_gh2<<<768, 256, 0, stream>>>(G, Ht, Yt);
        k_az2<<<512, 256, 0, stream>>>(A, Yt, Zf);
        k_updm<<<256, 256, 0, stream>>>(Zf, wuhT, wxb, bu, S2, zb, h, Ht, t);
    }
    k_dec<<<256, 256, 0, stream>>>(h, Wd, bd, out);
}